// Round 3
// baseline (459.862 us; speedup 1.0000x reference)
//
#include <hip/hip_runtime.h>

#define NEG_SLOPE 0.2f

__device__ __forceinline__ float leaky(float v) { return v > 0.f ? v : NEG_SLOPE * v; }

// ---------------- CSR build ----------------

__global__ void k_count(const int* __restrict__ dst, int E, int* __restrict__ deg) {
    int i = blockIdx.x * blockDim.x + threadIdx.x;
    if (i < E) atomicAdd(&deg[dst[i]], 1);
}

// single-block exclusive scan; +1 per node folds in the self loop.
__global__ void k_scan(const int* __restrict__ deg, int* __restrict__ rowptr, int N) {
    __shared__ int wsum[16];
    __shared__ int sbase;
    int tid = threadIdx.x;
    int lane = tid & 63, wid = tid >> 6;
    if (tid == 0) { sbase = 0; rowptr[0] = 0; }
    __syncthreads();
    for (int start = 0; start < N; start += 1024) {
        int i = start + tid;
        int v = (i < N) ? deg[i] + 1 : 0;   // +1: self loop
        int s = v;
        #pragma unroll
        for (int off = 1; off < 64; off <<= 1) {
            int t = __shfl_up(s, off);
            if (lane >= off) s += t;
        }
        if (lane == 63) wsum[wid] = s;
        __syncthreads();
        if (wid == 0) {
            int w = (lane < 16) ? wsum[lane] : 0;
            #pragma unroll
            for (int off = 1; off < 16; off <<= 1) {
                int t = __shfl_up(w, off);
                if (lane >= off) w += t;
            }
            if (lane < 16) wsum[lane] = w;
        }
        __syncthreads();
        int waveoff = (wid == 0) ? 0 : wsum[wid - 1];
        int incl = sbase + waveoff + s;
        if (i < N) rowptr[i + 1] = incl;
        __syncthreads();
        if (tid == 1023) sbase = incl;
        __syncthreads();
    }
}

// csr entries are uint16 (N < 65536): halves footprint to 3.3 MB (fits one XCD L2)
__global__ void k_scatter(const int* __restrict__ src, const int* __restrict__ dst,
                          int E, int N, const int* __restrict__ rowptr,
                          int* __restrict__ cursor, unsigned short* __restrict__ csr) {
    int i = blockIdx.x * blockDim.x + threadIdx.x;
    if (i < E) {
        int d = dst[i];
        int pos = rowptr[d] + atomicAdd(&cursor[d], 1);
        __builtin_nontemporal_store((unsigned short)src[i], &csr[pos]);
    } else if (i < E + N) {
        int n = i - E;
        int pos = rowptr[n] + atomicAdd(&cursor[n], 1);
        __builtin_nontemporal_store((unsigned short)n, &csr[pos]);
    }
}

// ---------------- per-layer precompute ----------------
// consts[0]=cs1=W1.as1, consts[1]=cd1=W1.ad1, consts[2..66)=W2@as2, consts[66..130)=W2@ad2
__global__ void k_prep(const float* __restrict__ W1, const float* __restrict__ as1,
                       const float* __restrict__ ad1, const float* __restrict__ W2,
                       const float* __restrict__ as2, const float* __restrict__ ad2,
                       float* __restrict__ consts) {
    int i = threadIdx.x;  // 64 threads
    float a = 0.f, b = 0.f;
    for (int j = 0; j < 64; j++) {
        float w = W2[i * 64 + j];
        a += w * as2[j];
        b += w * ad2[j];
    }
    consts[2 + i] = a;
    consts[66 + i] = b;
    if (i == 0) { float c = 0.f; for (int j = 0; j < 64; j++) c += W1[j] * as1[j]; consts[0] = c; }
    if (i == 1) { float c = 0.f; for (int j = 0; j < 64; j++) c += W1[j] * ad1[j]; consts[1] = c; }
}

// ---------------- layer 1 (fused: scalar GAT + s2/d2 attention scalars) ----------------
__global__ void k_l1(const float* __restrict__ x, const int* __restrict__ rowptr,
                     const unsigned short* __restrict__ csr,
                     const float* __restrict__ consts, const float* __restrict__ W1,
                     const float* __restrict__ b1,
                     float* __restrict__ agg1, float* __restrict__ s2,
                     float* __restrict__ d2, int N) {
    int n = (blockIdx.x * blockDim.x + threadIdx.x) >> 6;
    int lane = threadIdx.x & 63;
    if (n >= N) return;
    float cs = consts[0], cd = consts[1];
    float dn = x[n] * cd;
    int beg = rowptr[n], end = rowptr[n + 1];
    float m = -1e30f, den = 0.f, num = 0.f;
    for (int e = beg + lane; e < end; e += 64) {
        float v = x[csr[e]];
        float el = leaky(fmaf(v, cs, dn));
        float mnew = fmaxf(m, el);
        float sc = __expf(m - mnew);
        float w = __expf(el - mnew);
        den = den * sc + w;
        num = num * sc + w * v;
        m = mnew;
    }
    #pragma unroll
    for (int off = 32; off; off >>= 1) {
        float m2 = __shfl_xor(m, off);
        float dd = __shfl_xor(den, off);
        float n2 = __shfl_xor(num, off);
        float M = fmaxf(m, m2);
        float sa = __expf(m - M), sb = __expf(m2 - M);
        den = den * sa + dd * sb;
        num = num * sa + n2 * sb;
        m = M;
    }
    float agg = num / den;                           // all lanes (butterfly)
    // fused s2/d2: h1row[lane] = relu(agg*W1[lane]+b1[lane])
    float t = fmaxf(fmaf(agg, W1[lane], b1[lane]), 0.f);
    float a = t * consts[2 + lane];
    float b = t * consts[66 + lane];
    #pragma unroll
    for (int off = 32; off; off >>= 1) {
        a += __shfl_xor(a, off);
        b += __shfl_xor(b, off);
    }
    if (lane == 0) { agg1[n] = agg; s2[n] = a; d2[n] = b; }
}

// ---------------- layer 2 ----------------
__global__ void k_layer2(const float* __restrict__ agg1, const float* __restrict__ s2,
                         const float* __restrict__ d2v, const int* __restrict__ rowptr,
                         const unsigned short* __restrict__ csr,
                         const float* __restrict__ W1, const float* __restrict__ b1,
                         const float* __restrict__ W2, const float* __restrict__ b2,
                         const float* __restrict__ W3,
                         float* __restrict__ h3, int N) {
    int n = (blockIdx.x * blockDim.x + threadIdx.x) >> 6;
    int lane = threadIdx.x & 63;
    if (n >= N) return;
    int beg = rowptr[n], end = rowptr[n + 1];
    float dn = d2v[n];
    // pass A: (m, den)
    float m = -1e30f, den = 0.f;
    for (int e = beg + lane; e < end; e += 64) {
        float el = leaky(s2[csr[e]] + dn);
        float mnew = fmaxf(m, el);
        den = den * __expf(m - mnew) + __expf(el - mnew);
        m = mnew;
    }
    #pragma unroll
    for (int off = 32; off; off >>= 1) {
        float m2 = __shfl_xor(m, off), dd = __shfl_xor(den, off);
        float M = fmaxf(m, m2);
        den = den * __expf(m - M) + dd * __expf(m2 - M);
        m = M;
    }
    float inv_den = 1.f / den;
    float w1l = W1[lane], b1l = b1[lane];
    float acc = 0.f;
    // pass B: per 64-edge chunk, lane-parallel (alpha, srcval) then shfl-broadcast
    for (int cb = beg; cb < end; cb += 64) {
        int e = cb + lane;
        float alpha = 0.f, av = 0.f;
        if (e < end) {
            int sIdx = csr[e];
            av = agg1[sIdx];
            alpha = __expf(leaky(s2[sIdx] + dn) - m) * inv_den;
        }
        int cnt = min(64, end - cb);
        for (int k = 0; k < cnt; k++) {
            float a = __shfl(alpha, k);
            float v = __shfl(av, k);
            float t = fmaxf(fmaf(v, w1l, b1l), 0.f);
            acc = fmaf(a, t, acc);
        }
    }
    // epilogue: h2 = relu(acc @ W2 + b2); h3 = h2 . W3
    float o = b2[lane];
    for (int f = 0; f < 64; f++) {
        float af = __shfl(acc, f);
        o = fmaf(af, W2[f * 64 + lane], o);
    }
    o = fmaxf(o, 0.f);
    float c = o * W3[lane];
    #pragma unroll
    for (int off = 32; off; off >>= 1) c += __shfl_xor(c, off);
    if (lane == 0) h3[n] = c;
}

// ---------------- layer 3: scalar GAT, bias, write out ----------------
__global__ void k_l3(const float* __restrict__ val, const int* __restrict__ rowptr,
                     const unsigned short* __restrict__ csr,
                     const float* __restrict__ cs_p, const float* __restrict__ cd_p,
                     const float* __restrict__ bias,
                     float* __restrict__ out, int N) {
    int n = (blockIdx.x * blockDim.x + threadIdx.x) >> 6;
    int lane = threadIdx.x & 63;
    if (n >= N) return;
    float cs = cs_p[0], cd = cd_p[0];
    float dn = val[n] * cd;
    int beg = rowptr[n], end = rowptr[n + 1];
    float m = -1e30f, den = 0.f, num = 0.f;
    for (int e = beg + lane; e < end; e += 64) {
        float v = val[csr[e]];
        float el = leaky(fmaf(v, cs, dn));
        float mnew = fmaxf(m, el);
        float sc = __expf(m - mnew);
        float w = __expf(el - mnew);
        den = den * sc + w;
        num = num * sc + w * v;
        m = mnew;
    }
    #pragma unroll
    for (int off = 32; off; off >>= 1) {
        float m2 = __shfl_xor(m, off);
        float dd = __shfl_xor(den, off);
        float n2 = __shfl_xor(num, off);
        float M = fmaxf(m, m2);
        float sa = __expf(m - M), sb = __expf(m2 - M);
        den = den * sa + dd * sb;
        num = num * sa + n2 * sb;
        m = M;
    }
    if (lane == 0) out[n] = num / den + bias[0];
}

// ---------------- launch ----------------

extern "C" void kernel_launch(void* const* d_in, const int* in_sizes, int n_in,
                              void* d_out, int out_size, void* d_ws, size_t ws_size,
                              hipStream_t stream) {
    const int N = in_sizes[0];          // x is [N,1]
    const int E = in_sizes[1] / 2;      // edge_index [2,E]
    const int Etot = E + N;

    const float* x   = (const float*)d_in[0];
    const int*   ei  = (const int*)d_in[1];
    const int*   src = ei;
    const int*   dst = ei + E;
    const float* W1  = (const float*)d_in[3];
    const float* as1 = (const float*)d_in[4];
    const float* ad1 = (const float*)d_in[5];
    const float* b1  = (const float*)d_in[6];
    const float* W2  = (const float*)d_in[7];
    const float* as2 = (const float*)d_in[8];
    const float* ad2 = (const float*)d_in[9];
    const float* b2  = (const float*)d_in[10];
    const float* W3  = (const float*)d_in[11];
    const float* as3 = (const float*)d_in[12];
    const float* ad3 = (const float*)d_in[13];
    const float* b3  = (const float*)d_in[14];
    float* out = (float*)d_out;

    char* p = (char*)d_ws;
    auto alloc = [&](size_t bytes) {
        char* r = p;
        p += (bytes + 255) & ~(size_t)255;
        return r;
    };
    // deg and cursor adjacent: zeroed by one memset
    int*   deg     = (int*)alloc((size_t)N * 4);
    int*   cursor  = (int*)alloc((size_t)N * 4);
    size_t zero_bytes = (size_t)((char*)cursor - (char*)deg) + (size_t)N * 4;
    int*   rowptr  = (int*)alloc((size_t)(N + 1) * 4);
    float* consts  = (float*)alloc(130 * sizeof(float));
    unsigned short* csr = (unsigned short*)alloc((size_t)Etot * 2);
    float* agg1    = (float*)alloc((size_t)N * 4);
    float* s2      = (float*)alloc((size_t)N * 4);
    float* d2      = (float*)alloc((size_t)N * 4);
    float* h3      = (float*)alloc((size_t)N * 4);

    const int B = 256;
    int gE   = (E + B - 1) / B;
    int gEt  = (Etot + B - 1) / B;
    int gW   = (int)(((size_t)N * 64 + B - 1) / B);   // wave-per-node kernels

    hipMemsetAsync(deg, 0, zero_bytes, stream);
    hipLaunchKernelGGL(k_count,   dim3(gE),  dim3(B), 0, stream, dst, E, deg);
    hipLaunchKernelGGL(k_scan,    dim3(1),   dim3(1024), 0, stream, deg, rowptr, N);
    hipLaunchKernelGGL(k_scatter, dim3(gEt), dim3(B), 0, stream, src, dst, E, N, rowptr, cursor, csr);
    hipLaunchKernelGGL(k_prep,    dim3(1),   dim3(64), 0, stream, W1, as1, ad1, W2, as2, ad2, consts);

    // layer 1 (+ fused s2/d2)
    hipLaunchKernelGGL(k_l1, dim3(gW), dim3(B), 0, stream,
                       x, rowptr, csr, consts, W1, b1, agg1, s2, d2, N);
    // layer 2: produces h3 (= h2 . W3) directly
    hipLaunchKernelGGL(k_layer2, dim3(gW), dim3(B), 0, stream,
                       agg1, s2, d2, rowptr, csr, W1, b1, W2, b2, W3, h3, N);
    // layer 3: scalar GAT on h3, + b3, straight to output
    hipLaunchKernelGGL(k_l3, dim3(gW), dim3(B), 0, stream,
                       h3, rowptr, csr, as3, ad3, b3, out, N);
}

// Round 4
// 275.289 us; speedup vs baseline: 1.6705x; 1.6705x over previous
//
#include <hip/hip_runtime.h>

#define NEG_SLOPE 0.2f
#define BSH 8
#define BSZ 256                 // nodes per bucket
#define SC_PT 16                // edges per thread in bucket scatter
#define SC_CHUNK (256 * SC_PT)  // edges per block in bucket scatter
#define STAGE_MAX 24576         // u16 entries staged per bucket (48 KB; mean fill ~8.7K)

__device__ __forceinline__ float leaky(float v) { return v > 0.f ? v : NEG_SLOPE * v; }

// ---------------- bucketed CSR build ----------------

// pass 1: per-bucket edge counts (LDS-aggregated)
__global__ void k_bhist(const int* __restrict__ dst, int E, int NB, int* __restrict__ bcount) {
    __shared__ int h[256];
    int tid = threadIdx.x;
    for (int i = tid; i < NB; i += 256) h[i] = 0;
    __syncthreads();
    for (int i = blockIdx.x * 256 + tid; i < E; i += gridDim.x * 256)
        atomicAdd(&h[dst[i] >> BSH], 1);
    __syncthreads();
    for (int i = tid; i < NB; i += 256) if (h[i]) atomicAdd(&bcount[i], h[i]);
}

// pass 2: exclusive scan of bucket counts (single block, NB <= 256)
__global__ void k_bscan(const int* __restrict__ bcount, int NB,
                        int* __restrict__ bbase, int* __restrict__ bcursor) {
    __shared__ int wsum[4];
    int tid = threadIdx.x, lane = tid & 63, wid = tid >> 6;
    int v = (tid < NB) ? bcount[tid] : 0;
    int s = v;
    #pragma unroll
    for (int off = 1; off < 64; off <<= 1) { int t = __shfl_up(s, off); if (lane >= off) s += t; }
    if (lane == 63) wsum[wid] = s;
    __syncthreads();
    int woff = 0;
    for (int w = 0; w < wid; w++) woff += wsum[w];
    int incl = woff + s;
    if (tid == 0) bbase[0] = 0;
    if (tid < NB) { bbase[tid + 1] = incl; bcursor[tid] = incl - v; }
}

// pass 3: block-aggregated scatter into per-bucket contiguous regions
__global__ void k_bscatter(const int* __restrict__ src, const int* __restrict__ dst,
                           int E, int NB, int* __restrict__ bcursor,
                           unsigned int* __restrict__ bentry) {
    __shared__ int h[256], base[256], lcur[256];
    int tid = threadIdx.x;
    int b0 = blockIdx.x * SC_CHUNK;
    for (int i = tid; i < 256; i += 256) { h[i] = 0; lcur[i] = 0; }
    __syncthreads();
    int d[SC_PT], s[SC_PT];
    #pragma unroll
    for (int k = 0; k < SC_PT; k++) {
        int i = b0 + k * 256 + tid;
        if (i < E) { d[k] = dst[i]; s[k] = src[i]; atomicAdd(&h[d[k] >> BSH], 1); }
        else d[k] = -1;
    }
    __syncthreads();
    if (tid < NB && h[tid]) base[tid] = atomicAdd(&bcursor[tid], h[tid]);
    __syncthreads();
    #pragma unroll
    for (int k = 0; k < SC_PT; k++) {
        if (d[k] >= 0) {
            int b = d[k] >> BSH;
            int l = atomicAdd(&lcur[b], 1);
            bentry[base[b] + l] = ((unsigned)s[k] << BSH) | (unsigned)(d[k] & (BSZ - 1));
        }
    }
}

// pass 4: one block per bucket — local degrees, LDS scan, LDS scatter, dense write-out
__global__ void k_build(const unsigned int* __restrict__ bentry, const int* __restrict__ bbase,
                        int N, int NB, int Etot,
                        int* __restrict__ rowptr, unsigned short* __restrict__ csr) {
    __shared__ int deg[256], lcur[256];
    __shared__ int wsum[4];
    __shared__ unsigned short stage[STAGE_MAX];
    int b = blockIdx.x, tid = threadIdx.x, lane = tid & 63, wid = tid >> 6;
    int node0 = b << BSH;
    int nvalid = min(256, N - node0);
    int ebeg = bbase[b], cnt = bbase[b + 1] - ebeg;
    deg[tid] = (tid < nvalid) ? 1 : 0;   // self loop
    __syncthreads();
    for (int i = tid; i < cnt; i += 256)
        atomicAdd(&deg[bentry[ebeg + i] & (BSZ - 1)], 1);
    __syncthreads();
    int v = deg[tid], s = v;
    #pragma unroll
    for (int off = 1; off < 64; off <<= 1) { int t = __shfl_up(s, off); if (lane >= off) s += t; }
    if (lane == 63) wsum[wid] = s;
    __syncthreads();
    int woff = 0;
    for (int w = 0; w < wid; w++) woff += wsum[w];
    int excl = woff + s - v;
    int gstart = ebeg + node0;           // edges before bucket + self loops before bucket
    if (tid < nvalid) rowptr[node0 + tid] = gstart + excl;
    if (b == NB - 1 && tid == 0) rowptr[N] = Etot;
    // self loop placed first in each row
    if (tid < nvalid) { stage[excl] = (unsigned short)(node0 + tid); lcur[tid] = excl + 1; }
    else lcur[tid] = excl;
    __syncthreads();
    for (int i = tid; i < cnt; i += 256) {
        unsigned int e = bentry[ebeg + i];
        int pos = atomicAdd(&lcur[e & (BSZ - 1)], 1);
        stage[pos] = (unsigned short)(e >> BSH);
    }
    __syncthreads();
    int total = cnt + nvalid;
    for (int i = tid; i < total; i += 256) csr[gstart + i] = stage[i];
}

// ---------------- per-layer precompute ----------------
// consts[0]=cs1=W1.as1, consts[1]=cd1=W1.ad1, consts[2..66)=W2@as2, consts[66..130)=W2@ad2
__global__ void k_prep(const float* __restrict__ W1, const float* __restrict__ as1,
                       const float* __restrict__ ad1, const float* __restrict__ W2,
                       const float* __restrict__ as2, const float* __restrict__ ad2,
                       float* __restrict__ consts) {
    int i = threadIdx.x;  // 64 threads
    float a = 0.f, b = 0.f;
    for (int j = 0; j < 64; j++) {
        float w = W2[i * 64 + j];
        a += w * as2[j];
        b += w * ad2[j];
    }
    consts[2 + i] = a;
    consts[66 + i] = b;
    if (i == 0) { float c = 0.f; for (int j = 0; j < 64; j++) c += W1[j] * as1[j]; consts[0] = c; }
    if (i == 1) { float c = 0.f; for (int j = 0; j < 64; j++) c += W1[j] * ad1[j]; consts[1] = c; }
}

// ---------------- layer 1 (fused: scalar GAT + s2/d2 attention scalars) ----------------
__global__ void k_l1(const float* __restrict__ x, const int* __restrict__ rowptr,
                     const unsigned short* __restrict__ csr,
                     const float* __restrict__ consts, const float* __restrict__ W1,
                     const float* __restrict__ b1,
                     float* __restrict__ agg1, float* __restrict__ s2,
                     float* __restrict__ d2, int N) {
    int n = (blockIdx.x * blockDim.x + threadIdx.x) >> 6;
    int lane = threadIdx.x & 63;
    if (n >= N) return;
    float cs = consts[0], cd = consts[1];
    float dn = x[n] * cd;
    int beg = rowptr[n], end = rowptr[n + 1];
    float m = -1e30f, den = 0.f, num = 0.f;
    for (int e = beg + lane; e < end; e += 64) {
        float v = x[csr[e]];
        float el = leaky(fmaf(v, cs, dn));
        float mnew = fmaxf(m, el);
        float sc = __expf(m - mnew);
        float w = __expf(el - mnew);
        den = den * sc + w;
        num = num * sc + w * v;
        m = mnew;
    }
    #pragma unroll
    for (int off = 32; off; off >>= 1) {
        float m2 = __shfl_xor(m, off);
        float dd = __shfl_xor(den, off);
        float n2 = __shfl_xor(num, off);
        float M = fmaxf(m, m2);
        float sa = __expf(m - M), sb = __expf(m2 - M);
        den = den * sa + dd * sb;
        num = num * sa + n2 * sb;
        m = M;
    }
    float agg = num / den;
    float t = fmaxf(fmaf(agg, W1[lane], b1[lane]), 0.f);
    float a = t * consts[2 + lane];
    float b = t * consts[66 + lane];
    #pragma unroll
    for (int off = 32; off; off >>= 1) {
        a += __shfl_xor(a, off);
        b += __shfl_xor(b, off);
    }
    if (lane == 0) { agg1[n] = agg; s2[n] = a; d2[n] = b; }
}

// ---------------- layer 2 ----------------
__global__ void k_layer2(const float* __restrict__ agg1, const float* __restrict__ s2,
                         const float* __restrict__ d2v, const int* __restrict__ rowptr,
                         const unsigned short* __restrict__ csr,
                         const float* __restrict__ W1, const float* __restrict__ b1,
                         const float* __restrict__ W2, const float* __restrict__ b2,
                         const float* __restrict__ W3,
                         float* __restrict__ h3, int N) {
    int n = (blockIdx.x * blockDim.x + threadIdx.x) >> 6;
    int lane = threadIdx.x & 63;
    if (n >= N) return;
    int beg = rowptr[n], end = rowptr[n + 1];
    float dn = d2v[n];
    float m = -1e30f, den = 0.f;
    for (int e = beg + lane; e < end; e += 64) {
        float el = leaky(s2[csr[e]] + dn);
        float mnew = fmaxf(m, el);
        den = den * __expf(m - mnew) + __expf(el - mnew);
        m = mnew;
    }
    #pragma unroll
    for (int off = 32; off; off >>= 1) {
        float m2 = __shfl_xor(m, off), dd = __shfl_xor(den, off);
        float M = fmaxf(m, m2);
        den = den * __expf(m - M) + dd * __expf(m2 - M);
        m = M;
    }
    float inv_den = 1.f / den;
    float w1l = W1[lane], b1l = b1[lane];
    float acc = 0.f;
    for (int cb = beg; cb < end; cb += 64) {
        int e = cb + lane;
        float alpha = 0.f, av = 0.f;
        if (e < end) {
            int sIdx = csr[e];
            av = agg1[sIdx];
            alpha = __expf(leaky(s2[sIdx] + dn) - m) * inv_den;
        }
        int cnt = min(64, end - cb);
        for (int k = 0; k < cnt; k++) {
            float a = __shfl(alpha, k);
            float vv = __shfl(av, k);
            float t = fmaxf(fmaf(vv, w1l, b1l), 0.f);
            acc = fmaf(a, t, acc);
        }
    }
    float o = b2[lane];
    for (int f = 0; f < 64; f++) {
        float af = __shfl(acc, f);
        o = fmaf(af, W2[f * 64 + lane], o);
    }
    o = fmaxf(o, 0.f);
    float c = o * W3[lane];
    #pragma unroll
    for (int off = 32; off; off >>= 1) c += __shfl_xor(c, off);
    if (lane == 0) h3[n] = c;
}

// ---------------- layer 3 ----------------
__global__ void k_l3(const float* __restrict__ val, const int* __restrict__ rowptr,
                     const unsigned short* __restrict__ csr,
                     const float* __restrict__ cs_p, const float* __restrict__ cd_p,
                     const float* __restrict__ bias,
                     float* __restrict__ out, int N) {
    int n = (blockIdx.x * blockDim.x + threadIdx.x) >> 6;
    int lane = threadIdx.x & 63;
    if (n >= N) return;
    float cs = cs_p[0], cd = cd_p[0];
    float dn = val[n] * cd;
    int beg = rowptr[n], end = rowptr[n + 1];
    float m = -1e30f, den = 0.f, num = 0.f;
    for (int e = beg + lane; e < end; e += 64) {
        float v = val[csr[e]];
        float el = leaky(fmaf(v, cs, dn));
        float mnew = fmaxf(m, el);
        float sc = __expf(m - mnew);
        float w = __expf(el - mnew);
        den = den * sc + w;
        num = num * sc + w * v;
        m = mnew;
    }
    #pragma unroll
    for (int off = 32; off; off >>= 1) {
        float m2 = __shfl_xor(m, off);
        float dd = __shfl_xor(den, off);
        float n2 = __shfl_xor(num, off);
        float M = fmaxf(m, m2);
        float sa = __expf(m - M), sb = __expf(m2 - M);
        den = den * sa + dd * sb;
        num = num * sa + n2 * sb;
        m = M;
    }
    if (lane == 0) out[n] = num / den + bias[0];
}

// ---------------- launch ----------------

extern "C" void kernel_launch(void* const* d_in, const int* in_sizes, int n_in,
                              void* d_out, int out_size, void* d_ws, size_t ws_size,
                              hipStream_t stream) {
    const int N = in_sizes[0];          // x is [N,1]
    const int E = in_sizes[1] / 2;      // edge_index [2,E]
    const int Etot = E + N;
    const int NB = (N + BSZ - 1) >> BSH;

    const float* x   = (const float*)d_in[0];
    const int*   ei  = (const int*)d_in[1];
    const int*   src = ei;
    const int*   dst = ei + E;
    const float* W1  = (const float*)d_in[3];
    const float* as1 = (const float*)d_in[4];
    const float* ad1 = (const float*)d_in[5];
    const float* b1  = (const float*)d_in[6];
    const float* W2  = (const float*)d_in[7];
    const float* as2 = (const float*)d_in[8];
    const float* ad2 = (const float*)d_in[9];
    const float* b2  = (const float*)d_in[10];
    const float* W3  = (const float*)d_in[11];
    const float* as3 = (const float*)d_in[12];
    const float* ad3 = (const float*)d_in[13];
    const float* b3  = (const float*)d_in[14];
    float* out = (float*)d_out;

    char* p = (char*)d_ws;
    auto alloc = [&](size_t bytes) {
        char* r = p;
        p += (bytes + 255) & ~(size_t)255;
        return r;
    };
    int*   bcount  = (int*)alloc(256 * 4);
    int*   bbase   = (int*)alloc(257 * 4);
    int*   bcursor = (int*)alloc(256 * 4);
    int*   rowptr  = (int*)alloc((size_t)(N + 1) * 4);
    float* consts  = (float*)alloc(130 * sizeof(float));
    unsigned int*   bentry = (unsigned int*)alloc((size_t)E * 4);
    unsigned short* csr    = (unsigned short*)alloc((size_t)Etot * 2);
    float* agg1    = (float*)alloc((size_t)N * 4);
    float* s2      = (float*)alloc((size_t)N * 4);
    float* d2      = (float*)alloc((size_t)N * 4);
    float* h3      = (float*)alloc((size_t)N * 4);

    const int B = 256;
    int gH  = min(1024, (E + B - 1) / B);
    int gS  = (E + SC_CHUNK - 1) / SC_CHUNK;
    int gW  = (int)(((size_t)N * 64 + B - 1) / B);   // wave-per-node kernels

    hipMemsetAsync(bcount, 0, 256 * 4, stream);
    hipLaunchKernelGGL(k_bhist,    dim3(gH), dim3(B), 0, stream, dst, E, NB, bcount);
    hipLaunchKernelGGL(k_bscan,    dim3(1),  dim3(B), 0, stream, bcount, NB, bbase, bcursor);
    hipLaunchKernelGGL(k_bscatter, dim3(gS), dim3(B), 0, stream, src, dst, E, NB, bcursor, bentry);
    hipLaunchKernelGGL(k_build,    dim3(NB), dim3(B), 0, stream, bentry, bbase, N, NB, Etot, rowptr, csr);
    hipLaunchKernelGGL(k_prep,     dim3(1),  dim3(64), 0, stream, W1, as1, ad1, W2, as2, ad2, consts);

    hipLaunchKernelGGL(k_l1, dim3(gW), dim3(B), 0, stream,
                       x, rowptr, csr, consts, W1, b1, agg1, s2, d2, N);
    hipLaunchKernelGGL(k_layer2, dim3(gW), dim3(B), 0, stream,
                       agg1, s2, d2, rowptr, csr, W1, b1, W2, b2, W3, h3, N);
    hipLaunchKernelGGL(k_l3, dim3(gW), dim3(B), 0, stream,
                       h3, rowptr, csr, as3, ad3, b3, out, N);
}

// Round 5
// 253.297 us; speedup vs baseline: 1.8155x; 1.0868x over previous
//
#include <hip/hip_runtime.h>

#define NEG_SLOPE 0.2f
#define BSH 8
#define BSZ 256                 // nodes per bucket
#define SC_PT 16                // edges per thread in bucket scatter
#define SC_CHUNK (256 * SC_PT)  // edges per block in bucket scatter
#define STAGE_MAX 24576         // u16 entries staged per bucket (48 KB)

__device__ __forceinline__ float leaky(float v) { return v > 0.f ? v : NEG_SLOPE * v; }

// ---------------- bucketed CSR build (unchanged from R4 — verified exact) ----------------

__global__ void k_bhist(const int* __restrict__ dst, int E, int NB, int* __restrict__ bcount) {
    __shared__ int h[256];
    int tid = threadIdx.x;
    for (int i = tid; i < NB; i += 256) h[i] = 0;
    __syncthreads();
    for (int i = blockIdx.x * 256 + tid; i < E; i += gridDim.x * 256)
        atomicAdd(&h[dst[i] >> BSH], 1);
    __syncthreads();
    for (int i = tid; i < NB; i += 256) if (h[i]) atomicAdd(&bcount[i], h[i]);
}

__global__ void k_bscan(const int* __restrict__ bcount, int NB,
                        int* __restrict__ bbase, int* __restrict__ bcursor) {
    __shared__ int wsum[4];
    int tid = threadIdx.x, lane = tid & 63, wid = tid >> 6;
    int v = (tid < NB) ? bcount[tid] : 0;
    int s = v;
    #pragma unroll
    for (int off = 1; off < 64; off <<= 1) { int t = __shfl_up(s, off); if (lane >= off) s += t; }
    if (lane == 63) wsum[wid] = s;
    __syncthreads();
    int woff = 0;
    for (int w = 0; w < wid; w++) woff += wsum[w];
    int incl = woff + s;
    if (tid == 0) bbase[0] = 0;
    if (tid < NB) { bbase[tid + 1] = incl; bcursor[tid] = incl - v; }
}

__global__ void k_bscatter(const int* __restrict__ src, const int* __restrict__ dst,
                           int E, int NB, int* __restrict__ bcursor,
                           unsigned int* __restrict__ bentry) {
    __shared__ int h[256], base[256], lcur[256];
    int tid = threadIdx.x;
    int b0 = blockIdx.x * SC_CHUNK;
    for (int i = tid; i < 256; i += 256) { h[i] = 0; lcur[i] = 0; }
    __syncthreads();
    int d[SC_PT], s[SC_PT];
    #pragma unroll
    for (int k = 0; k < SC_PT; k++) {
        int i = b0 + k * 256 + tid;
        if (i < E) { d[k] = dst[i]; s[k] = src[i]; atomicAdd(&h[d[k] >> BSH], 1); }
        else d[k] = -1;
    }
    __syncthreads();
    if (tid < NB && h[tid]) base[tid] = atomicAdd(&bcursor[tid], h[tid]);
    __syncthreads();
    #pragma unroll
    for (int k = 0; k < SC_PT; k++) {
        if (d[k] >= 0) {
            int b = d[k] >> BSH;
            int l = atomicAdd(&lcur[b], 1);
            bentry[base[b] + l] = ((unsigned)s[k] << BSH) | (unsigned)(d[k] & (BSZ - 1));
        }
    }
}

__global__ void k_build(const unsigned int* __restrict__ bentry, const int* __restrict__ bbase,
                        int N, int NB, int Etot,
                        int* __restrict__ rowptr, unsigned short* __restrict__ csr) {
    __shared__ int deg[256], lcur[256];
    __shared__ int wsum[4];
    __shared__ unsigned short stage[STAGE_MAX];
    int b = blockIdx.x, tid = threadIdx.x, lane = tid & 63, wid = tid >> 6;
    int node0 = b << BSH;
    int nvalid = min(256, N - node0);
    int ebeg = bbase[b], cnt = bbase[b + 1] - ebeg;
    deg[tid] = (tid < nvalid) ? 1 : 0;
    __syncthreads();
    for (int i = tid; i < cnt; i += 256)
        atomicAdd(&deg[bentry[ebeg + i] & (BSZ - 1)], 1);
    __syncthreads();
    int v = deg[tid], s = v;
    #pragma unroll
    for (int off = 1; off < 64; off <<= 1) { int t = __shfl_up(s, off); if (lane >= off) s += t; }
    if (lane == 63) wsum[wid] = s;
    __syncthreads();
    int woff = 0;
    for (int w = 0; w < wid; w++) woff += wsum[w];
    int excl = woff + s - v;
    int gstart = ebeg + node0;
    if (tid < nvalid) rowptr[node0 + tid] = gstart + excl;
    if (b == NB - 1 && tid == 0) rowptr[N] = Etot;
    if (tid < nvalid) { stage[excl] = (unsigned short)(node0 + tid); lcur[tid] = excl + 1; }
    else lcur[tid] = excl;
    __syncthreads();
    for (int i = tid; i < cnt; i += 256) {
        unsigned int e = bentry[ebeg + i];
        int pos = atomicAdd(&lcur[e & (BSZ - 1)], 1);
        stage[pos] = (unsigned short)(e >> BSH);
    }
    __syncthreads();
    int total = cnt + nvalid;
    for (int i = tid; i < total; i += 256) csr[gstart + i] = stage[i];
}

// ---------------- precompute ----------------
// consts: [0]=cs1 [1]=cd1 [2..66)=W2@as2 [66..130)=W2@ad2
//         [130..194)=Tsorted [194..258)=rank(float) [258..322)=sign
__global__ void k_prep(const float* __restrict__ W1, const float* __restrict__ as1,
                       const float* __restrict__ ad1, const float* __restrict__ b1,
                       const float* __restrict__ W2, const float* __restrict__ as2,
                       const float* __restrict__ ad2, float* __restrict__ consts) {
    __shared__ float ts[64];
    int i = threadIdx.x;  // 64 threads
    float a = 0.f, b = 0.f;
    for (int j = 0; j < 64; j++) {
        float w = W2[i * 64 + j];
        a += w * as2[j];
        b += w * ad2[j];
    }
    consts[2 + i] = a;
    consts[66 + i] = b;
    if (i == 0) { float c = 0.f; for (int j = 0; j < 64; j++) c += W1[j] * as1[j]; consts[0] = c; }
    if (i == 1) { float c = 0.f; for (int j = 0; j < 64; j++) c += W1[j] * ad1[j]; consts[1] = c; }
    // thresholds for layer-2 relu bucketing
    float w1 = W1[i];
    float t = (w1 != 0.f) ? (-b1[i] / w1) : 1e30f;
    ts[i] = t;
    __syncthreads();
    int r = 0;
    for (int k = 0; k < 64; k++) {
        float tk = ts[k];
        r += (tk < t) || (tk == t && k < i);
    }
    consts[130 + r] = t;                    // sorted scatter (ranks are a permutation)
    consts[194 + i] = (float)r;
    consts[258 + i] = (w1 > 0.f) ? 1.f : (w1 < 0.f ? -1.f : 0.f);
}

// ---------------- layer 1: scalar GAT (two-pass max/sum) + fused s2/d2 ----------------
__global__ __launch_bounds__(256) void k_l1(
        const float* __restrict__ x, const int* __restrict__ rowptr,
        const unsigned short* __restrict__ csr, const float* __restrict__ consts,
        const float* __restrict__ W1, const float* __restrict__ b1,
        float2* __restrict__ sa2, float* __restrict__ d2, int N) {
    int n = (blockIdx.x * blockDim.x + threadIdx.x) >> 6;
    int lane = threadIdx.x & 63;
    if (n >= N) return;
    float cs = consts[0], cd = consts[1];
    float dn = x[n] * cd;
    int beg = rowptr[n], end = rowptr[n + 1];
    float mx = -1e30f;
    for (int e = beg + lane; e < end; e += 64)
        mx = fmaxf(mx, leaky(fmaf(x[csr[e]], cs, dn)));
    #pragma unroll
    for (int off = 32; off; off >>= 1) mx = fmaxf(mx, __shfl_xor(mx, off));
    float den = 0.f, num = 0.f;
    for (int e = beg + lane; e < end; e += 64) {
        float v = x[csr[e]];
        float w = __expf(leaky(fmaf(v, cs, dn)) - mx);
        den += w;
        num = fmaf(w, v, num);
    }
    #pragma unroll
    for (int off = 32; off; off >>= 1) {
        den += __shfl_xor(den, off);
        num += __shfl_xor(num, off);
    }
    float agg = num / den;
    float t = fmaxf(fmaf(agg, W1[lane], b1[lane]), 0.f);
    float a = t * consts[2 + lane];
    float b = t * consts[66 + lane];
    #pragma unroll
    for (int off = 32; off; off >>= 1) {
        a += __shfl_xor(a, off);
        b += __shfl_xor(b, off);
    }
    if (lane == 0) { sa2[n] = make_float2(a, agg); d2[n] = b; }
}

// ---------------- layer 2: threshold-bucketed relu aggregation ----------------
__global__ __launch_bounds__(256) void k_layer2(
        const float2* __restrict__ sa2, const float* __restrict__ d2v,
        const int* __restrict__ rowptr, const unsigned short* __restrict__ csr,
        const float* __restrict__ consts,
        const float* __restrict__ W1, const float* __restrict__ b1,
        const float* __restrict__ W2, const float* __restrict__ b2,
        const float* __restrict__ W3,
        float* __restrict__ h3, int N) {
    __shared__ float Ts[64];
    __shared__ float bk0[4][66], bk1[4][66];
    __shared__ float accs[4][64];
    int tid = threadIdx.x, lane = tid & 63, wid = tid >> 6;
    if (tid < 64) Ts[tid] = consts[130 + tid];
    __syncthreads();
    int n = (blockIdx.x * blockDim.x + tid) >> 6;
    if (n >= N) return;

    float w1l = W1[lane], b1l = b1[lane];
    int   rk  = (int)consts[194 + lane];
    float sg  = consts[258 + lane];
    float dn  = d2v[n];
    int beg = rowptr[n], end = rowptr[n + 1];

    // pass A: global max of logits
    float mx = -1e30f;
    for (int e = beg + lane; e < end; e += 64)
        mx = fmaxf(mx, leaky(sa2[csr[e]].x + dn));
    #pragma unroll
    for (int off = 32; off; off >>= 1) mx = fmaxf(mx, __shfl_xor(mx, off));

    // zero buckets (per-wave private)
    bk0[wid][lane] = 0.f; bk1[wid][lane] = 0.f;
    if (lane == 0) { bk0[wid][64] = 0.f; bk1[wid][64] = 0.f; }
    __asm__ volatile("" ::: "memory");

    // pass B: rank each edge by av against sorted thresholds, 2 LDS float atomics
    for (int e = beg + lane; e < end; e += 64) {
        float2 f2 = sa2[csr[e]];
        float w = __expf(leaky(f2.x + dn) - mx);
        float av = f2.y;
        int p = 0;
        #pragma unroll
        for (int step = 32; step; step >>= 1)
            if (Ts[p + step - 1] < av) p += step;
        atomicAdd(&bk0[wid][p], w);
        atomicAdd(&bk1[wid][p], w * av);
    }
    __asm__ volatile("" ::: "memory");

    // inclusive prefix sums over buckets 0..63 (lane l holds prefix through l)
    float p0 = bk0[wid][lane], p1 = bk1[wid][lane];
    #pragma unroll
    for (int off = 1; off < 64; off <<= 1) {
        float t0 = __shfl_up(p0, off), t1 = __shfl_up(p1, off);
        if (lane >= off) { p0 += t0; p1 += t1; }
    }
    float T0 = __shfl(p0, 63) + bk0[wid][64];   // = den
    float T1 = __shfl(p1, 63) + bk1[wid][64];
    float P0r = __shfl(p0, rk), P1r = __shfl(p1, rk);

    float acc;
    if (sg > 0.f)      acc = fmaf(w1l, T1 - P1r, b1l * (T0 - P0r));
    else if (sg < 0.f) acc = fmaf(w1l, P1r, b1l * P0r);
    else               acc = fmaxf(b1l, 0.f) * T0;
    acc /= T0;

    // epilogue: h2 = relu(acc @ W2 + b2); h3 = h2 . W3
    accs[wid][lane] = acc;
    __asm__ volatile("" ::: "memory");
    float o = b2[lane];
    #pragma unroll 8
    for (int f = 0; f < 64; f++)
        o = fmaf(accs[wid][f], W2[f * 64 + lane], o);   // LDS broadcast + L1-hot W2
    o = fmaxf(o, 0.f);
    float c = o * W3[lane];
    #pragma unroll
    for (int off = 32; off; off >>= 1) c += __shfl_xor(c, off);
    if (lane == 0) h3[n] = c;
}

// ---------------- layer 3: scalar GAT (two-pass), bias, output ----------------
__global__ __launch_bounds__(256) void k_l3(
        const float* __restrict__ val, const int* __restrict__ rowptr,
        const unsigned short* __restrict__ csr,
        const float* __restrict__ cs_p, const float* __restrict__ cd_p,
        const float* __restrict__ bias, float* __restrict__ out, int N) {
    int n = (blockIdx.x * blockDim.x + threadIdx.x) >> 6;
    int lane = threadIdx.x & 63;
    if (n >= N) return;
    float cs = cs_p[0], cd = cd_p[0];
    float dn = val[n] * cd;
    int beg = rowptr[n], end = rowptr[n + 1];
    float mx = -1e30f;
    for (int e = beg + lane; e < end; e += 64)
        mx = fmaxf(mx, leaky(fmaf(val[csr[e]], cs, dn)));
    #pragma unroll
    for (int off = 32; off; off >>= 1) mx = fmaxf(mx, __shfl_xor(mx, off));
    float den = 0.f, num = 0.f;
    for (int e = beg + lane; e < end; e += 64) {
        float v = val[csr[e]];
        float w = __expf(leaky(fmaf(v, cs, dn)) - mx);
        den += w;
        num = fmaf(w, v, num);
    }
    #pragma unroll
    for (int off = 32; off; off >>= 1) {
        den += __shfl_xor(den, off);
        num += __shfl_xor(num, off);
    }
    if (lane == 0) out[n] = num / den + bias[0];
}

// ---------------- launch ----------------

extern "C" void kernel_launch(void* const* d_in, const int* in_sizes, int n_in,
                              void* d_out, int out_size, void* d_ws, size_t ws_size,
                              hipStream_t stream) {
    const int N = in_sizes[0];
    const int E = in_sizes[1] / 2;
    const int Etot = E + N;
    const int NB = (N + BSZ - 1) >> BSH;

    const float* x   = (const float*)d_in[0];
    const int*   ei  = (const int*)d_in[1];
    const int*   src = ei;
    const int*   dst = ei + E;
    const float* W1  = (const float*)d_in[3];
    const float* as1 = (const float*)d_in[4];
    const float* ad1 = (const float*)d_in[5];
    const float* b1  = (const float*)d_in[6];
    const float* W2  = (const float*)d_in[7];
    const float* as2 = (const float*)d_in[8];
    const float* ad2 = (const float*)d_in[9];
    const float* b2  = (const float*)d_in[10];
    const float* W3  = (const float*)d_in[11];
    const float* as3 = (const float*)d_in[12];
    const float* ad3 = (const float*)d_in[13];
    const float* b3  = (const float*)d_in[14];
    float* out = (float*)d_out;

    char* p = (char*)d_ws;
    auto alloc = [&](size_t bytes) {
        char* r = p;
        p += (bytes + 255) & ~(size_t)255;
        return r;
    };
    int*   bcount  = (int*)alloc(256 * 4);
    int*   bbase   = (int*)alloc(257 * 4);
    int*   bcursor = (int*)alloc(256 * 4);
    int*   rowptr  = (int*)alloc((size_t)(N + 1) * 4);
    float* consts  = (float*)alloc(322 * sizeof(float));
    unsigned int*   bentry = (unsigned int*)alloc((size_t)E * 4);
    unsigned short* csr    = (unsigned short*)alloc((size_t)Etot * 2);
    float2* sa2    = (float2*)alloc((size_t)N * 8);
    float* d2      = (float*)alloc((size_t)N * 4);
    float* h3      = (float*)alloc((size_t)N * 4);

    const int B = 256;
    int gH  = min(1024, (E + B - 1) / B);
    int gS  = (E + SC_CHUNK - 1) / SC_CHUNK;
    int gW  = (int)(((size_t)N * 64 + B - 1) / B);

    hipMemsetAsync(bcount, 0, 256 * 4, stream);
    hipLaunchKernelGGL(k_bhist,    dim3(gH), dim3(B), 0, stream, dst, E, NB, bcount);
    hipLaunchKernelGGL(k_bscan,    dim3(1),  dim3(B), 0, stream, bcount, NB, bbase, bcursor);
    hipLaunchKernelGGL(k_bscatter, dim3(gS), dim3(B), 0, stream, src, dst, E, NB, bcursor, bentry);
    hipLaunchKernelGGL(k_build,    dim3(NB), dim3(B), 0, stream, bentry, bbase, N, NB, Etot, rowptr, csr);
    hipLaunchKernelGGL(k_prep,     dim3(1),  dim3(64), 0, stream, W1, as1, ad1, b1, W2, as2, ad2, consts);

    hipLaunchKernelGGL(k_l1, dim3(gW), dim3(B), 0, stream,
                       x, rowptr, csr, consts, W1, b1, sa2, d2, N);
    hipLaunchKernelGGL(k_layer2, dim3(gW), dim3(B), 0, stream,
                       sa2, d2, rowptr, csr, consts, W1, b1, W2, b2, W3, h3, N);
    hipLaunchKernelGGL(k_l3, dim3(gW), dim3(B), 0, stream,
                       h3, rowptr, csr, as3, ad3, b3, out, N);
}

// Round 6
// 235.800 us; speedup vs baseline: 1.9502x; 1.0742x over previous
//
#include <hip/hip_runtime.h>

#define NEG_SLOPE 0.2f
#define BSH 8
#define BSZ 256                 // nodes per bucket
#define SC_PT 16                // edges per thread in bucket scatter
#define SC_CHUNK (256 * SC_PT)  // edges per block in bucket scatter
#define STAGE_MAX 24576         // u16 entries staged per bucket (48 KB)

__device__ __forceinline__ float leaky(float v) { return v > 0.f ? v : NEG_SLOPE * v; }

// ---------------- bucketed CSR build (unchanged — verified exact) ----------------

__global__ void k_bhist(const int* __restrict__ dst, int E, int NB, int* __restrict__ bcount) {
    __shared__ int h[256];
    int tid = threadIdx.x;
    for (int i = tid; i < NB; i += 256) h[i] = 0;
    __syncthreads();
    for (int i = blockIdx.x * 256 + tid; i < E; i += gridDim.x * 256)
        atomicAdd(&h[dst[i] >> BSH], 1);
    __syncthreads();
    for (int i = tid; i < NB; i += 256) if (h[i]) atomicAdd(&bcount[i], h[i]);
}

__global__ void k_bscan(const int* __restrict__ bcount, int NB,
                        int* __restrict__ bbase, int* __restrict__ bcursor) {
    __shared__ int wsum[4];
    int tid = threadIdx.x, lane = tid & 63, wid = tid >> 6;
    int v = (tid < NB) ? bcount[tid] : 0;
    int s = v;
    #pragma unroll
    for (int off = 1; off < 64; off <<= 1) { int t = __shfl_up(s, off); if (lane >= off) s += t; }
    if (lane == 63) wsum[wid] = s;
    __syncthreads();
    int woff = 0;
    for (int w = 0; w < wid; w++) woff += wsum[w];
    int incl = woff + s;
    if (tid == 0) bbase[0] = 0;
    if (tid < NB) { bbase[tid + 1] = incl; bcursor[tid] = incl - v; }
}

__global__ void k_bscatter(const int* __restrict__ src, const int* __restrict__ dst,
                           int E, int NB, int* __restrict__ bcursor,
                           unsigned int* __restrict__ bentry) {
    __shared__ int h[256], base[256], lcur[256];
    int tid = threadIdx.x;
    int b0 = blockIdx.x * SC_CHUNK;
    for (int i = tid; i < 256; i += 256) { h[i] = 0; lcur[i] = 0; }
    __syncthreads();
    int d[SC_PT], s[SC_PT];
    #pragma unroll
    for (int k = 0; k < SC_PT; k++) {
        int i = b0 + k * 256 + tid;
        if (i < E) { d[k] = dst[i]; s[k] = src[i]; atomicAdd(&h[d[k] >> BSH], 1); }
        else d[k] = -1;
    }
    __syncthreads();
    if (tid < NB && h[tid]) base[tid] = atomicAdd(&bcursor[tid], h[tid]);
    __syncthreads();
    #pragma unroll
    for (int k = 0; k < SC_PT; k++) {
        if (d[k] >= 0) {
            int b = d[k] >> BSH;
            int l = atomicAdd(&lcur[b], 1);
            bentry[base[b] + l] = ((unsigned)s[k] << BSH) | (unsigned)(d[k] & (BSZ - 1));
        }
    }
}

__global__ void k_build(const unsigned int* __restrict__ bentry, const int* __restrict__ bbase,
                        int N, int NB, int Etot,
                        int* __restrict__ rowptr, unsigned short* __restrict__ csr) {
    __shared__ int deg[256], lcur[256];
    __shared__ int wsum[4];
    __shared__ unsigned short stage[STAGE_MAX];
    int b = blockIdx.x, tid = threadIdx.x, lane = tid & 63, wid = tid >> 6;
    int node0 = b << BSH;
    int nvalid = min(256, N - node0);
    int ebeg = bbase[b], cnt = bbase[b + 1] - ebeg;
    deg[tid] = (tid < nvalid) ? 1 : 0;
    __syncthreads();
    for (int i = tid; i < cnt; i += 256)
        atomicAdd(&deg[bentry[ebeg + i] & (BSZ - 1)], 1);
    __syncthreads();
    int v = deg[tid], s = v;
    #pragma unroll
    for (int off = 1; off < 64; off <<= 1) { int t = __shfl_up(s, off); if (lane >= off) s += t; }
    if (lane == 63) wsum[wid] = s;
    __syncthreads();
    int woff = 0;
    for (int w = 0; w < wid; w++) woff += wsum[w];
    int excl = woff + s - v;
    int gstart = ebeg + node0;
    if (tid < nvalid) rowptr[node0 + tid] = gstart + excl;
    if (b == NB - 1 && tid == 0) rowptr[N] = Etot;
    if (tid < nvalid) { stage[excl] = (unsigned short)(node0 + tid); lcur[tid] = excl + 1; }
    else lcur[tid] = excl;
    __syncthreads();
    for (int i = tid; i < cnt; i += 256) {
        unsigned int e = bentry[ebeg + i];
        int pos = atomicAdd(&lcur[e & (BSZ - 1)], 1);
        stage[pos] = (unsigned short)(e >> BSH);
    }
    __syncthreads();
    int total = cnt + nvalid;
    for (int i = tid; i < total; i += 256) csr[gstart + i] = stage[i];
}

// ---------------- precompute ----------------
// consts: [0]=cs1 [1]=cd1 [2..66)=W2@as2 [66..130)=W2@ad2
//         [130..194)=Tsorted [194..258)=rank(float) [258..322)=sign
__global__ void k_prep(const float* __restrict__ W1, const float* __restrict__ as1,
                       const float* __restrict__ ad1, const float* __restrict__ b1,
                       const float* __restrict__ W2, const float* __restrict__ as2,
                       const float* __restrict__ ad2, float* __restrict__ consts) {
    __shared__ float ts[64];
    int i = threadIdx.x;  // 64 threads
    float a = 0.f, b = 0.f;
    for (int j = 0; j < 64; j++) {
        float w = W2[i * 64 + j];
        a += w * as2[j];
        b += w * ad2[j];
    }
    consts[2 + i] = a;
    consts[66 + i] = b;
    if (i == 0) { float c = 0.f; for (int j = 0; j < 64; j++) c += W1[j] * as1[j]; consts[0] = c; }
    if (i == 1) { float c = 0.f; for (int j = 0; j < 64; j++) c += W1[j] * ad1[j]; consts[1] = c; }
    float w1 = W1[i];
    float t = (w1 != 0.f) ? (-b1[i] / w1) : 1e30f;
    ts[i] = t;
    __syncthreads();
    int r = 0;
    for (int k = 0; k < 64; k++) {
        float tk = ts[k];
        r += (tk < t) || (tk == t && k < i);
    }
    consts[130 + r] = t;
    consts[194 + i] = (float)r;
    consts[258 + i] = (w1 > 0.f) ? 1.f : (w1 < 0.f ? -1.f : 0.f);
}

// ---------------- layer 1: single-pass scalar GAT (self-logit shift) + fused s2/d2 ----------------
__global__ __launch_bounds__(256) void k_l1(
        const float* __restrict__ x, const int* __restrict__ rowptr,
        const unsigned short* __restrict__ csr, const float* __restrict__ consts,
        const float* __restrict__ W1, const float* __restrict__ b1,
        float2* __restrict__ sa2, float* __restrict__ d2, int N) {
    int n = (blockIdx.x * blockDim.x + threadIdx.x) >> 6;
    int lane = threadIdx.x & 63;
    if (n >= N) return;
    float cs = consts[0], cd = consts[1];
    float xn = x[n];
    float dn = xn * cd;
    // shift by the self-loop logit: softmax is shift-invariant; den >= 1 guaranteed
    float mself = leaky(fmaf(xn, cs, dn));
    int beg = rowptr[n], end = rowptr[n + 1];
    float den = 0.f, num = 0.f;
    for (int e = beg + lane; e < end; e += 64) {
        float v = x[csr[e]];
        float w = __expf(leaky(fmaf(v, cs, dn)) - mself);
        den += w;
        num = fmaf(w, v, num);
    }
    #pragma unroll
    for (int off = 32; off; off >>= 1) {
        den += __shfl_xor(den, off);
        num += __shfl_xor(num, off);
    }
    float agg = num / den;
    float t = fmaxf(fmaf(agg, W1[lane], b1[lane]), 0.f);
    float a = t * consts[2 + lane];
    float b = t * consts[66 + lane];
    #pragma unroll
    for (int off = 32; off; off >>= 1) {
        a += __shfl_xor(a, off);
        b += __shfl_xor(b, off);
    }
    if (lane == 0) { sa2[n] = make_float2(a, agg); d2[n] = b; }
}

// ---------------- layer 2: single-pass threshold-bucketed relu aggregation ----------------
__global__ __launch_bounds__(256) void k_layer2(
        const float2* __restrict__ sa2, const float* __restrict__ d2v,
        const int* __restrict__ rowptr, const unsigned short* __restrict__ csr,
        const float* __restrict__ consts,
        const float* __restrict__ W1, const float* __restrict__ b1,
        const float* __restrict__ W2, const float* __restrict__ b2,
        const float* __restrict__ W3,
        float* __restrict__ h3, int N) {
    __shared__ float Ts[64];
    __shared__ float bk0[4][66], bk1[4][66];
    __shared__ float accs[4][64];
    int tid = threadIdx.x, lane = tid & 63, wid = tid >> 6;
    if (tid < 64) Ts[tid] = consts[130 + tid];
    __syncthreads();
    int n = (blockIdx.x * blockDim.x + tid) >> 6;
    if (n >= N) return;

    float w1l = W1[lane], b1l = b1[lane];
    int   rk  = (int)consts[194 + lane];
    float sg  = consts[258 + lane];
    float dn  = d2v[n];
    // shift by self-loop logit (shift-invariant): no max pass needed
    float mx  = leaky(sa2[n].x + dn);
    int beg = rowptr[n], end = rowptr[n + 1];

    bk0[wid][lane] = 0.f; bk1[wid][lane] = 0.f;
    if (lane == 0) { bk0[wid][64] = 0.f; bk1[wid][64] = 0.f; }
    __asm__ volatile("" ::: "memory");

    // single pass: rank each edge's av against sorted thresholds, 2 LDS float atomics
    for (int e = beg + lane; e < end; e += 64) {
        float2 f2 = sa2[csr[e]];
        float w = __expf(leaky(f2.x + dn) - mx);
        float av = f2.y;
        int p = 0;
        #pragma unroll
        for (int step = 32; step; step >>= 1)
            if (Ts[p + step - 1] < av) p += step;
        atomicAdd(&bk0[wid][p], w);
        atomicAdd(&bk1[wid][p], w * av);
    }
    __asm__ volatile("" ::: "memory");

    // inclusive prefix sums over buckets 0..63
    float p0 = bk0[wid][lane], p1 = bk1[wid][lane];
    #pragma unroll
    for (int off = 1; off < 64; off <<= 1) {
        float t0 = __shfl_up(p0, off), t1 = __shfl_up(p1, off);
        if (lane >= off) { p0 += t0; p1 += t1; }
    }
    float T0 = __shfl(p0, 63) + bk0[wid][64];   // = den
    float T1 = __shfl(p1, 63) + bk1[wid][64];
    float P0r = __shfl(p0, rk), P1r = __shfl(p1, rk);

    float acc;
    if (sg > 0.f)      acc = fmaf(w1l, T1 - P1r, b1l * (T0 - P0r));
    else if (sg < 0.f) acc = fmaf(w1l, P1r, b1l * P0r);
    else               acc = fmaxf(b1l, 0.f) * T0;
    acc /= T0;

    // epilogue: h2 = relu(acc @ W2 + b2); h3 = h2 . W3
    accs[wid][lane] = acc;
    __asm__ volatile("" ::: "memory");
    float o = b2[lane];
    #pragma unroll 8
    for (int f = 0; f < 64; f++)
        o = fmaf(accs[wid][f], W2[f * 64 + lane], o);
    o = fmaxf(o, 0.f);
    float c = o * W3[lane];
    #pragma unroll
    for (int off = 32; off; off >>= 1) c += __shfl_xor(c, off);
    if (lane == 0) h3[n] = c;
}

// ---------------- layer 3: single-pass scalar GAT (self-logit shift), bias, output ----------------
__global__ __launch_bounds__(256) void k_l3(
        const float* __restrict__ val, const int* __restrict__ rowptr,
        const unsigned short* __restrict__ csr,
        const float* __restrict__ cs_p, const float* __restrict__ cd_p,
        const float* __restrict__ bias, float* __restrict__ out, int N) {
    int n = (blockIdx.x * blockDim.x + threadIdx.x) >> 6;
    int lane = threadIdx.x & 63;
    if (n >= N) return;
    float cs = cs_p[0], cd = cd_p[0];
    float vn = val[n];
    float dn = vn * cd;
    float mself = leaky(fmaf(vn, cs, dn));
    int beg = rowptr[n], end = rowptr[n + 1];
    float den = 0.f, num = 0.f;
    for (int e = beg + lane; e < end; e += 64) {
        float v = val[csr[e]];
        float w = __expf(leaky(fmaf(v, cs, dn)) - mself);
        den += w;
        num = fmaf(w, v, num);
    }
    #pragma unroll
    for (int off = 32; off; off >>= 1) {
        den += __shfl_xor(den, off);
        num += __shfl_xor(num, off);
    }
    if (lane == 0) out[n] = num / den + bias[0];
}

// ---------------- launch ----------------

extern "C" void kernel_launch(void* const* d_in, const int* in_sizes, int n_in,
                              void* d_out, int out_size, void* d_ws, size_t ws_size,
                              hipStream_t stream) {
    const int N = in_sizes[0];
    const int E = in_sizes[1] / 2;
    const int Etot = E + N;
    const int NB = (N + BSZ - 1) >> BSH;

    const float* x   = (const float*)d_in[0];
    const int*   ei  = (const int*)d_in[1];
    const int*   src = ei;
    const int*   dst = ei + E;
    const float* W1  = (const float*)d_in[3];
    const float* as1 = (const float*)d_in[4];
    const float* ad1 = (const float*)d_in[5];
    const float* b1  = (const float*)d_in[6];
    const float* W2  = (const float*)d_in[7];
    const float* as2 = (const float*)d_in[8];
    const float* ad2 = (const float*)d_in[9];
    const float* b2  = (const float*)d_in[10];
    const float* W3  = (const float*)d_in[11];
    const float* as3 = (const float*)d_in[12];
    const float* ad3 = (const float*)d_in[13];
    const float* b3  = (const float*)d_in[14];
    float* out = (float*)d_out;

    char* p = (char*)d_ws;
    auto alloc = [&](size_t bytes) {
        char* r = p;
        p += (bytes + 255) & ~(size_t)255;
        return r;
    };
    int*   bcount  = (int*)alloc(256 * 4);
    int*   bbase   = (int*)alloc(257 * 4);
    int*   bcursor = (int*)alloc(256 * 4);
    int*   rowptr  = (int*)alloc((size_t)(N + 1) * 4);
    float* consts  = (float*)alloc(322 * sizeof(float));
    unsigned int*   bentry = (unsigned int*)alloc((size_t)E * 4);
    unsigned short* csr    = (unsigned short*)alloc((size_t)Etot * 2);
    float2* sa2    = (float2*)alloc((size_t)N * 8);
    float* d2      = (float*)alloc((size_t)N * 4);
    float* h3      = (float*)alloc((size_t)N * 4);

    const int B = 256;
    int gH  = min(1024, (E + B - 1) / B);
    int gS  = (E + SC_CHUNK - 1) / SC_CHUNK;
    int gW  = (int)(((size_t)N * 64 + B - 1) / B);

    hipMemsetAsync(bcount, 0, 256 * 4, stream);
    hipLaunchKernelGGL(k_bhist,    dim3(gH), dim3(B), 0, stream, dst, E, NB, bcount);
    hipLaunchKernelGGL(k_bscan,    dim3(1),  dim3(B), 0, stream, bcount, NB, bbase, bcursor);
    hipLaunchKernelGGL(k_bscatter, dim3(gS), dim3(B), 0, stream, src, dst, E, NB, bcursor, bentry);
    hipLaunchKernelGGL(k_build,    dim3(NB), dim3(B), 0, stream, bentry, bbase, N, NB, Etot, rowptr, csr);
    hipLaunchKernelGGL(k_prep,     dim3(1),  dim3(64), 0, stream, W1, as1, ad1, b1, W2, as2, ad2, consts);

    hipLaunchKernelGGL(k_l1, dim3(gW), dim3(B), 0, stream,
                       x, rowptr, csr, consts, W1, b1, sa2, d2, N);
    hipLaunchKernelGGL(k_layer2, dim3(gW), dim3(B), 0, stream,
                       sa2, d2, rowptr, csr, consts, W1, b1, W2, b2, W3, h3, N);
    hipLaunchKernelGGL(k_l3, dim3(gW), dim3(B), 0, stream,
                       h3, rowptr, csr, as3, ad3, b3, out, N);
}

// Round 7
// 224.848 us; speedup vs baseline: 2.0452x; 1.0487x over previous
//
#include <hip/hip_runtime.h>

#define NEG_SLOPE 0.2f
#define BSH 8
#define BSZ 256                 // nodes per bucket
#define SC_PT 16                // edges per thread in bucket scatter
#define SC_CHUNK (256 * SC_PT)  // edges per block in bucket scatter
#define STAGE_MAX 24576         // u16 entries staged per bucket (48 KB)

__device__ __forceinline__ float leaky(float v) { return v > 0.f ? v : NEG_SLOPE * v; }
__device__ __forceinline__ float rdlane(float v, int l) {
    return __uint_as_float(__builtin_amdgcn_readlane(__float_as_uint(v), l));
}

// ---------------- bucketed CSR build ----------------

__global__ void k_bhist(const int* __restrict__ dst, int E, int NB, int* __restrict__ bcount) {
    __shared__ int h[256];
    int tid = threadIdx.x;
    for (int i = tid; i < NB; i += 256) h[i] = 0;
    __syncthreads();
    for (int i = blockIdx.x * 256 + tid; i < E; i += gridDim.x * 256)
        atomicAdd(&h[dst[i] >> BSH], 1);
    __syncthreads();
    for (int i = tid; i < NB; i += 256) if (h[i]) atomicAdd(&bcount[i], h[i]);
}

// bucket scan (256 threads) + fused weight precompute
// consts: [0]=cs1 [1]=cd1 [2..66)=W2@as2 [66..130)=W2@ad2
//         [130..194)=Tsorted [194..258)=rank(float) [258..322)=sign
__global__ void k_bscan_prep(const int* __restrict__ bcount, int NB,
                             int* __restrict__ bbase, int* __restrict__ bcursor,
                             const float* __restrict__ W1, const float* __restrict__ as1,
                             const float* __restrict__ ad1, const float* __restrict__ b1,
                             const float* __restrict__ W2, const float* __restrict__ as2,
                             const float* __restrict__ ad2, float* __restrict__ consts) {
    __shared__ int wsum[4];
    __shared__ float ts[64];
    int tid = threadIdx.x, lane = tid & 63, wid = tid >> 6;
    // --- bucket exclusive scan ---
    int v = (tid < NB) ? bcount[tid] : 0;
    int s = v;
    #pragma unroll
    for (int off = 1; off < 64; off <<= 1) { int t = __shfl_up(s, off); if (lane >= off) s += t; }
    if (lane == 63) wsum[wid] = s;
    __syncthreads();
    int woff = 0;
    for (int w = 0; w < wid; w++) woff += wsum[w];
    int incl = woff + s;
    if (tid == 0) bbase[0] = 0;
    if (tid < NB) { bbase[tid + 1] = incl; bcursor[tid] = incl - v; }
    // --- weight precompute (threads 0..63) ---
    float t = 0.f;
    if (tid < 64) {
        float a = 0.f, b = 0.f;
        for (int j = 0; j < 64; j++) {
            float w = W2[tid * 64 + j];
            a += w * as2[j];
            b += w * ad2[j];
        }
        consts[2 + tid] = a;
        consts[66 + tid] = b;
        if (tid == 0) { float c = 0.f; for (int j = 0; j < 64; j++) c += W1[j] * as1[j]; consts[0] = c; }
        if (tid == 1) { float c = 0.f; for (int j = 0; j < 64; j++) c += W1[j] * ad1[j]; consts[1] = c; }
        float w1 = W1[tid];
        t = (w1 != 0.f) ? (-b1[tid] / w1) : 1e30f;
        ts[tid] = t;
    }
    __syncthreads();
    if (tid < 64) {
        float w1 = W1[tid];
        int r = 0;
        for (int k = 0; k < 64; k++) {
            float tk = ts[k];
            r += (tk < t) || (tk == t && k < tid);
        }
        consts[130 + r] = t;
        consts[194 + tid] = (float)r;
        consts[258 + tid] = (w1 > 0.f) ? 1.f : (w1 < 0.f ? -1.f : 0.f);
    }
}

__global__ void k_bscatter(const int* __restrict__ src, const int* __restrict__ dst,
                           int E, int NB, int* __restrict__ bcursor,
                           unsigned int* __restrict__ bentry) {
    __shared__ int h[256], base[256], lcur[256];
    int tid = threadIdx.x;
    int b0 = blockIdx.x * SC_CHUNK;
    for (int i = tid; i < 256; i += 256) { h[i] = 0; lcur[i] = 0; }
    __syncthreads();
    int d[SC_PT], s[SC_PT];
    #pragma unroll
    for (int k = 0; k < SC_PT; k++) {
        int i = b0 + k * 256 + tid;
        if (i < E) { d[k] = dst[i]; s[k] = src[i]; atomicAdd(&h[d[k] >> BSH], 1); }
        else d[k] = -1;
    }
    __syncthreads();
    if (tid < NB && h[tid]) base[tid] = atomicAdd(&bcursor[tid], h[tid]);
    __syncthreads();
    #pragma unroll
    for (int k = 0; k < SC_PT; k++) {
        if (d[k] >= 0) {
            int b = d[k] >> BSH;
            int l = atomicAdd(&lcur[b], 1);
            bentry[base[b] + l] = ((unsigned)s[k] << BSH) | (unsigned)(d[k] & (BSZ - 1));
        }
    }
}

__global__ void k_build(const unsigned int* __restrict__ bentry, const int* __restrict__ bbase,
                        int N, int NB, int Etot,
                        int* __restrict__ rowptr, unsigned short* __restrict__ csr) {
    __shared__ int deg[256], lcur[256];
    __shared__ int wsum[4];
    __shared__ unsigned short stage[STAGE_MAX];
    int b = blockIdx.x, tid = threadIdx.x, lane = tid & 63, wid = tid >> 6;
    int node0 = b << BSH;
    int nvalid = min(256, N - node0);
    int ebeg = bbase[b], cnt = bbase[b + 1] - ebeg;
    deg[tid] = (tid < nvalid) ? 1 : 0;
    __syncthreads();
    for (int i = tid; i < cnt; i += 256)
        atomicAdd(&deg[bentry[ebeg + i] & (BSZ - 1)], 1);
    __syncthreads();
    int v = deg[tid], s = v;
    #pragma unroll
    for (int off = 1; off < 64; off <<= 1) { int t = __shfl_up(s, off); if (lane >= off) s += t; }
    if (lane == 63) wsum[wid] = s;
    __syncthreads();
    int woff = 0;
    for (int w = 0; w < wid; w++) woff += wsum[w];
    int excl = woff + s - v;
    int gstart = ebeg + node0;
    if (tid < nvalid) rowptr[node0 + tid] = gstart + excl;
    if (b == NB - 1 && tid == 0) rowptr[N] = Etot;
    if (tid < nvalid) { stage[excl] = (unsigned short)(node0 + tid); lcur[tid] = excl + 1; }
    else lcur[tid] = excl;
    __syncthreads();
    for (int i = tid; i < cnt; i += 256) {
        unsigned int e = bentry[ebeg + i];
        int pos = atomicAdd(&lcur[e & (BSZ - 1)], 1);
        stage[pos] = (unsigned short)(e >> BSH);
    }
    __syncthreads();
    int total = cnt + nvalid;
    for (int i = tid; i < total; i += 256) csr[gstart + i] = stage[i];
}

// ---------------- layer 1: 2 nodes/wave, single-pass + fused s2/d2 ----------------
__global__ __launch_bounds__(256) void k_l1(
        const float* __restrict__ x, const int* __restrict__ rowptr,
        const unsigned short* __restrict__ csr, const float* __restrict__ consts,
        const float* __restrict__ W1, const float* __restrict__ b1,
        float2* __restrict__ sa2, float* __restrict__ d2, int N) {
    int w = (blockIdx.x * blockDim.x + threadIdx.x) >> 6;   // wave id
    int lane = threadIdx.x & 63;
    int hl = lane & 31, half = lane >> 5;
    int n = w * 2 + half;
    if (w * 2 >= N) return;
    int nn = min(n, N - 1);
    float cs = consts[0], cd = consts[1];
    float xn = x[nn];
    float dn = xn * cd;
    float mself = leaky(fmaf(xn, cs, dn));   // self-loop logit shift (softmax invariant)
    int beg = rowptr[nn], end = rowptr[nn + 1];
    float den = 0.f, num = 0.f;
    for (int e = beg + hl; e < end; e += 32) {
        float v = x[csr[e]];
        float wt = __expf(leaky(fmaf(v, cs, dn)) - mself);
        den += wt;
        num = fmaf(wt, v, num);
    }
    #pragma unroll
    for (int off = 16; off; off >>= 1) {       // 32-lane butterfly (stays in half)
        den += __shfl_xor(den, off);
        num += __shfl_xor(num, off);
    }
    float agg = num / den;
    float aggA = rdlane(agg, 0), aggB = rdlane(agg, 32);
    float w1l = W1[lane], b1l = b1[lane];
    float ca = consts[2 + lane], cb = consts[66 + lane];
    #pragma unroll
    for (int q = 0; q < 2; q++) {
        float aq = q ? aggB : aggA;
        float t = fmaxf(fmaf(aq, w1l, b1l), 0.f);
        float a = t * ca, b = t * cb;
        #pragma unroll
        for (int off = 32; off; off >>= 1) {
            a += __shfl_xor(a, off);
            b += __shfl_xor(b, off);
        }
        int nq = w * 2 + q;
        if (lane == 0 && nq < N) { sa2[nq] = make_float2(a, aq); d2[nq] = b; }
    }
}

// ---------------- layer 2: single-pass threshold-bucketed relu aggregation ----------------
__global__ __launch_bounds__(256) void k_layer2(
        const float2* __restrict__ sa2, const float* __restrict__ d2v,
        const int* __restrict__ rowptr, const unsigned short* __restrict__ csr,
        const float* __restrict__ consts,
        const float* __restrict__ W1, const float* __restrict__ b1,
        const float* __restrict__ W2, const float* __restrict__ b2,
        const float* __restrict__ W3,
        float* __restrict__ h3, int N) {
    __shared__ float Ts[64];
    __shared__ float bk0[4][66], bk1[4][66];
    int tid = threadIdx.x, lane = tid & 63, wid = tid >> 6;
    if (tid < 64) Ts[tid] = consts[130 + tid];
    __syncthreads();
    int n = (blockIdx.x * blockDim.x + tid) >> 6;
    if (n >= N) return;

    float w1l = W1[lane], b1l = b1[lane];
    int   rk  = (int)consts[194 + lane];
    float sg  = consts[258 + lane];
    float dn  = d2v[n];
    float mx  = leaky(sa2[n].x + dn);   // self-loop logit shift
    int beg = rowptr[n], end = rowptr[n + 1];

    bk0[wid][lane] = 0.f; bk1[wid][lane] = 0.f;
    if (lane == 0) { bk0[wid][64] = 0.f; bk1[wid][64] = 0.f; }
    __asm__ volatile("" ::: "memory");

    for (int e = beg + lane; e < end; e += 64) {
        float2 f2 = sa2[csr[e]];
        float w = __expf(leaky(f2.x + dn) - mx);
        float av = f2.y;
        int p = 0;
        #pragma unroll
        for (int step = 32; step; step >>= 1)
            if (Ts[p + step - 1] < av) p += step;
        atomicAdd(&bk0[wid][p], w);
        atomicAdd(&bk1[wid][p], w * av);
    }
    __asm__ volatile("" ::: "memory");

    // inclusive prefix sums over buckets 0..63
    float p0 = bk0[wid][lane], p1 = bk1[wid][lane];
    #pragma unroll
    for (int off = 1; off < 64; off <<= 1) {
        float t0 = __shfl_up(p0, off), t1 = __shfl_up(p1, off);
        if (lane >= off) { p0 += t0; p1 += t1; }
    }
    float T0 = rdlane(p0, 63) + bk0[wid][64];   // = den
    float T1 = rdlane(p1, 63) + bk1[wid][64];
    float P0r = __shfl(p0, rk), P1r = __shfl(p1, rk);

    float acc;
    if (sg > 0.f)      acc = fmaf(w1l, T1 - P1r, b1l * (T0 - P0r));
    else if (sg < 0.f) acc = fmaf(w1l, P1r, b1l * P0r);
    else               acc = fmaxf(b1l, 0.f) * T0;
    acc /= T0;

    // epilogue via readlane (no DS): h2 = relu(acc @ W2 + b2); h3 = h2 . W3
    float o = b2[lane];
    #pragma unroll
    for (int f = 0; f < 64; f++) {
        float af = rdlane(acc, f);
        o = fmaf(af, W2[f * 64 + lane], o);
    }
    o = fmaxf(o, 0.f);
    float c = o * W3[lane];
    #pragma unroll
    for (int off = 32; off; off >>= 1) c += __shfl_xor(c, off);
    if (lane == 0) h3[n] = c;
}

// ---------------- layer 3: 2 nodes/wave, single-pass, bias, output ----------------
__global__ __launch_bounds__(256) void k_l3(
        const float* __restrict__ val, const int* __restrict__ rowptr,
        const unsigned short* __restrict__ csr,
        const float* __restrict__ cs_p, const float* __restrict__ cd_p,
        const float* __restrict__ bias, float* __restrict__ out, int N) {
    int w = (blockIdx.x * blockDim.x + threadIdx.x) >> 6;
    int lane = threadIdx.x & 63;
    int hl = lane & 31, half = lane >> 5;
    int n = w * 2 + half;
    if (w * 2 >= N) return;
    int nn = min(n, N - 1);
    float cs = cs_p[0], cd = cd_p[0];
    float vn = val[nn];
    float dn = vn * cd;
    float mself = leaky(fmaf(vn, cs, dn));
    int beg = rowptr[nn], end = rowptr[nn + 1];
    float den = 0.f, num = 0.f;
    for (int e = beg + hl; e < end; e += 32) {
        float v = val[csr[e]];
        float wt = __expf(leaky(fmaf(v, cs, dn)) - mself);
        den += wt;
        num = fmaf(wt, v, num);
    }
    #pragma unroll
    for (int off = 16; off; off >>= 1) {
        den += __shfl_xor(den, off);
        num += __shfl_xor(num, off);
    }
    if (hl == 0 && n < N) out[n] = num / den + bias[0];
}

// ---------------- launch ----------------

extern "C" void kernel_launch(void* const* d_in, const int* in_sizes, int n_in,
                              void* d_out, int out_size, void* d_ws, size_t ws_size,
                              hipStream_t stream) {
    const int N = in_sizes[0];
    const int E = in_sizes[1] / 2;
    const int Etot = E + N;
    const int NB = (N + BSZ - 1) >> BSH;

    const float* x   = (const float*)d_in[0];
    const int*   ei  = (const int*)d_in[1];
    const int*   src = ei;
    const int*   dst = ei + E;
    const float* W1  = (const float*)d_in[3];
    const float* as1 = (const float*)d_in[4];
    const float* ad1 = (const float*)d_in[5];
    const float* b1  = (const float*)d_in[6];
    const float* W2  = (const float*)d_in[7];
    const float* as2 = (const float*)d_in[8];
    const float* ad2 = (const float*)d_in[9];
    const float* b2  = (const float*)d_in[10];
    const float* W3  = (const float*)d_in[11];
    const float* as3 = (const float*)d_in[12];
    const float* ad3 = (const float*)d_in[13];
    const float* b3  = (const float*)d_in[14];
    float* out = (float*)d_out;

    char* p = (char*)d_ws;
    auto alloc = [&](size_t bytes) {
        char* r = p;
        p += (bytes + 255) & ~(size_t)255;
        return r;
    };
    int*   bcount  = (int*)alloc(256 * 4);
    int*   bbase   = (int*)alloc(257 * 4);
    int*   bcursor = (int*)alloc(256 * 4);
    int*   rowptr  = (int*)alloc((size_t)(N + 1) * 4);
    float* consts  = (float*)alloc(322 * sizeof(float));
    unsigned int*   bentry = (unsigned int*)alloc((size_t)E * 4);
    unsigned short* csr    = (unsigned short*)alloc((size_t)Etot * 2);
    float2* sa2    = (float2*)alloc((size_t)N * 8);
    float* d2      = (float*)alloc((size_t)N * 4);
    float* h3      = (float*)alloc((size_t)N * 4);

    const int B = 256;
    int gH  = min(1024, (E + B - 1) / B);
    int gS  = (E + SC_CHUNK - 1) / SC_CHUNK;
    int gW  = (int)(((size_t)N * 64 + B - 1) / B);               // 1 node / wave (layer2)
    int nw2 = (N + 1) / 2;
    int gW2 = (int)(((size_t)nw2 * 64 + B - 1) / B);             // 2 nodes / wave (l1, l3)

    hipMemsetAsync(bcount, 0, 256 * 4, stream);
    hipLaunchKernelGGL(k_bhist,      dim3(gH), dim3(B), 0, stream, dst, E, NB, bcount);
    hipLaunchKernelGGL(k_bscan_prep, dim3(1),  dim3(B), 0, stream, bcount, NB, bbase, bcursor,
                       W1, as1, ad1, b1, W2, as2, ad2, consts);
    hipLaunchKernelGGL(k_bscatter,   dim3(gS), dim3(B), 0, stream, src, dst, E, NB, bcursor, bentry);
    hipLaunchKernelGGL(k_build,      dim3(NB), dim3(B), 0, stream, bentry, bbase, N, NB, Etot, rowptr, csr);

    hipLaunchKernelGGL(k_l1, dim3(gW2), dim3(B), 0, stream,
                       x, rowptr, csr, consts, W1, b1, sa2, d2, N);
    hipLaunchKernelGGL(k_layer2, dim3(gW), dim3(B), 0, stream,
                       sa2, d2, rowptr, csr, consts, W1, b1, W2, b2, W3, h3, N);
    hipLaunchKernelGGL(k_l3, dim3(gW2), dim3(B), 0, stream,
                       h3, rowptr, csr, as3, ad3, b3, out, N);
}